// Round 8
// baseline (235.895 us; speedup 1.0000x reference)
//
#include <hip/hip_runtime.h>
#include <hip/hip_bf16.h>

using bf16 = __hip_bfloat16;
typedef __attribute__((ext_vector_type(8))) short bf16x8;   // 8 bf16 = 4 VGPRs (MFMA A/B frag)
typedef __attribute__((ext_vector_type(4))) float f32x4;    // MFMA C/D frag

#define DEV __device__ __forceinline__

DEV float exp2fast(float x) { return __builtin_amdgcn_exp2f(x); }  // v_exp_f32 (2^x)

DEV void gload_lds16(const void* g, void* l) {
  __builtin_amdgcn_global_load_lds((const __attribute__((address_space(1))) void*)g,
                                   (__attribute__((address_space(3))) void*)l, 16, 0, 0);
}

DEV unsigned pk2(float lo, float hi) {   // pack 2 f32 -> 2 bf16
  union { bf16 h[2]; unsigned u; } z;
  z.h[0] = __float2bfloat16(lo);
  z.h[1] = __float2bfloat16(hi);
  return z.u;
}

// ---------------------------------------------------------------- prep: 3x cvt + 4x wtrans fused
struct PrepArgs {
  const float* x[3]; bf16* y[3];
  const float* W[4]; bf16* WT[4];
};

__global__ __launch_bounds__(256) void prep_kernel(PrepArgs a) {
  __shared__ float tile[32][33];
  const int b = blockIdx.x;
  if (b < 6144) {
    const int which = b >> 11, blk = b & 2047;
    const int i = blk * 256 + threadIdx.x;
    const float4* xv = (const float4*)a.x[which];
    float4 p = xv[i * 2];
    float4 q = xv[i * 2 + 1];
    union { bf16 h[8]; uint4 v; } u;
    u.h[0] = __float2bfloat16(p.x); u.h[1] = __float2bfloat16(p.y);
    u.h[2] = __float2bfloat16(p.z); u.h[3] = __float2bfloat16(p.w);
    u.h[4] = __float2bfloat16(q.x); u.h[5] = __float2bfloat16(q.y);
    u.h[6] = __float2bfloat16(q.z); u.h[7] = __float2bfloat16(q.w);
    *(uint4*)&a.y[which][(size_t)i * 8] = u.v;
  } else {
    const int w = (b - 6144) >> 10, blk = (b - 6144) & 1023;
    const float* W = a.W[w];
    bf16* WT = a.WT[w];
    const int tx = threadIdx.x & 31, ty = threadIdx.x >> 5;
    const int n0 = (blk & 31) * 32, k0 = (blk >> 5) * 32;
#pragma unroll
    for (int i = ty; i < 32; i += 8)
      tile[i][tx] = W[(size_t)(k0 + i) * 1024 + n0 + tx];
    __syncthreads();
#pragma unroll
    for (int i = ty; i < 32; i += 8)
      WT[(size_t)(n0 + i) * 1024 + k0 + tx] = __float2bfloat16(tile[tx][i]);
  }
}

// v (projected, bf16 [4096][1024]) -> VT [bh=32][dh=64][S=2048]
__global__ __launch_bounds__(256) void vtrans_kernel(const bf16* __restrict__ v,
                                                     bf16* __restrict__ VT) {
  __shared__ bf16 tile[64 * 64];
  const int t = threadIdx.x;
  const int bh = blockIdx.y, b = bh >> 4, h = bh & 15;
  const int s0 = blockIdx.x * 64;
  const int r0 = t >> 3, c8 = t & 7;
#pragma unroll
  for (int it = 0; it < 2; ++it) {
    int r = it * 32 + r0;
    uint4 d = *(const uint4*)&v[(size_t)(b * 2048 + s0 + r) * 1024 + h * 64 + c8 * 8];
    *(uint4*)&tile[r * 64 + ((c8 ^ (r >> 3)) * 8)] = d;
  }
  __syncthreads();
#pragma unroll
  for (int it = 0; it < 2; ++it) {
    int d = it * 32 + r0;
    int sc = c8 * 8;
    union { bf16 h[8]; uint4 v4; } u;
#pragma unroll
    for (int j = 0; j < 8; ++j) {
      int row = sc + j;
      u.h[j] = tile[row * 64 + (((d >> 3) ^ (row >> 3)) * 8) + (d & 7)];
    }
    *(uint4*)&VT[((size_t)bh * 64 + d) * 2048 + s0 + sc] = u.v4;
  }
}

// ---------------------------------------------------------------- GEMM BMx128, BK=32, 2-phase dbuf
// A [M][1024] bf16 row-major, BT [N][1024] bf16, bias f32[N]; out = relu(A@B+bias)
template <int BM, typename OutT>
DEV void gemm_core(const bf16* __restrict__ A, const bf16* __restrict__ BT,
                   const float* __restrict__ bias, OutT* __restrict__ out) {
  constexpr int K = 1024, N = 1024;
  constexpr int MI = BM / 32;           // A-frags per wave
  __shared__ bf16 ldsA[2][BM * 32];
  __shared__ bf16 ldsB[2][128 * 32];
  const int t = threadIdx.x;
  const int lane = t & 63, wid = t >> 6;
  const int wr = wid >> 1, wc = wid & 1;
  const int fr = lane & 15, fko = (lane >> 4) * 8;
  const size_t mBase = (size_t)blockIdx.y * BM;
  const size_t nBase = (size_t)blockIdx.x * 128;

  const int srow = t >> 2;              // 0..63
  const int scol = (t & 3) * 8;
  const bf16* gA = A + (mBase + srow) * K + scol;
  const bf16* gB = BT + (nBase + srow) * K + scol;
  const int ldst = wid * 512;           // wave-uniform LDS dest offset

  f32x4 acc[MI][4];
#pragma unroll
  for (int i = 0; i < MI; ++i)
#pragma unroll
    for (int j = 0; j < 4; ++j) acc[i][j] = (f32x4){0.f, 0.f, 0.f, 0.f};

  // prologue: stage K-step 0 into buf 0
  gload_lds16(gA, &ldsA[0][ldst]);
  if constexpr (BM == 128) gload_lds16(gA + 64 * K, &ldsA[0][ldst + 2048]);
  gload_lds16(gB, &ldsB[0][ldst]);
  gload_lds16(gB + 64 * K, &ldsB[0][ldst + 2048]);
  __syncthreads();

  int buf = 0;
  for (int k0 = 0; k0 < K; k0 += 32) {
    if (k0 + 32 < K) {
      const int kn = k0 + 32;
      gload_lds16(gA + kn, &ldsA[buf ^ 1][ldst]);
      if constexpr (BM == 128) gload_lds16(gA + 64 * K + kn, &ldsA[buf ^ 1][ldst + 2048]);
      gload_lds16(gB + kn, &ldsB[buf ^ 1][ldst]);
      gload_lds16(gB + 64 * K + kn, &ldsB[buf ^ 1][ldst + 2048]);
    }
    bf16x8 aF[MI], bF[4];
#pragma unroll
    for (int i = 0; i < MI; ++i)
      aF[i] = *(const bf16x8*)&ldsA[buf][(wr * (BM / 2) + i * 16 + fr) * 32 + fko];
#pragma unroll
    for (int j = 0; j < 4; ++j)
      bF[j] = *(const bf16x8*)&ldsB[buf][(wc * 64 + j * 16 + fr) * 32 + fko];
#pragma unroll
    for (int i = 0; i < MI; ++i)
#pragma unroll
      for (int j = 0; j < 4; ++j)
        acc[i][j] = __builtin_amdgcn_mfma_f32_16x16x32_bf16(aF[i], bF[j], acc[i][j], 0, 0, 0);
    __syncthreads();
    buf ^= 1;
  }

  const int orow = (int)mBase + wr * (BM / 2) + (lane >> 4) * 4;
  const int ocol = (int)nBase + wc * 64 + fr;
#pragma unroll
  for (int j = 0; j < 4; ++j) {
    const float bj = bias[ocol + j * 16];
#pragma unroll
    for (int i = 0; i < MI; ++i)
#pragma unroll
      for (int r = 0; r < 4; ++r) {
        float v = fmaxf(acc[i][j][r] + bj, 0.f);
        size_t idx = (size_t)(orow + i * 16 + r) * N + (ocol + j * 16);
        if constexpr (sizeof(OutT) == 2) out[idx] = __float2bfloat16(v);
        else out[idx] = v;
      }
  }
}

struct QKVArgs {
  const bf16* A[3];
  const bf16* BT[3];
  const float* bias[3];
  bf16* out[3];
};

__global__ __launch_bounds__(256) void gemm_qkv_kernel(QKVArgs args) {
  const int z = blockIdx.z;
  gemm_core<128, bf16>(args.A[z], args.BT[z], args.bias[z], args.out[z]);
}

__global__ __launch_bounds__(256) void gemm_out_kernel(const bf16* __restrict__ A,
                                                       const bf16* __restrict__ BT,
                                                       const float* __restrict__ bias,
                                                       float* __restrict__ out) {
  gemm_core<64, float>(A, BT, bias, out);   // 64x128 tiles -> 512 blocks = 2/CU
}

// ---------------------------------------------------------------- flash attention
// (causal, swapped QK^T, paired q-tiles, KVBLK=128, exp2-domain softmax, defer-max)
__global__ __launch_bounds__(256, 2) void attn_kernel(const bf16* __restrict__ Qb,
                                                      const bf16* __restrict__ Kb,
                                                      const bf16* __restrict__ VTb,
                                                      bf16* __restrict__ Ob) {
  constexpr int Dm = 1024, S = 2048;
  __shared__ bf16 ldsK[2][128 * 64];   // [kv][d]  32KB
  __shared__ bf16 ldsV[2][64 * 128];   // [d][kv]  32KB
  const int t = threadIdx.x, l = t & 63, wid = t >> 6;

  // XCD chunk swizzle (bijective, 512 = 8*64)
  const int lin = blockIdx.y * 16 + blockIdx.x;
  const int swz = (lin & 7) * 64 + (lin >> 3);
  const int bh = swz >> 4, pairp = swz & 15;
  const int b = bh >> 4, h = bh & 15;
  const int q4 = l & 15, fg = l >> 4;
  const bf16* Qg = Qb + (size_t)b * S * Dm + h * 64;
  const bf16* Kg = Kb + (size_t)b * S * Dm + h * 64;
  const bf16* VTg = VTb + (size_t)bh * 64 * S;

  // K staging geometry: per wave rows wid*32 + 8g + (l>>3); chunk (l&7)^(l>>3) (row&7 inv.)
  const int krow0 = wid * 32 + (l >> 3);
  const int kch = ((l & 7) ^ (l >> 3)) * 8;
  // V staging geometry: per wave d-rows wid*16 + 4g + (l>>4); chunk (l&15)^(row&15) per g
  const int vrl = l >> 4;          // 0..3
  const int vcb = l & 15;

  // bpermute indices for P^T B-frag build
  const int idx0 = ((q4 + ((l & 16) ? 32 : 0)) << 2);
  const int idx1 = idx0 + 64;

  constexpr float SC = 0.18033688f;   // 0.125 * log2(e)

  auto STAGE = [&](int tile, int bi) {
    const int kvb = tile * 128;
#pragma unroll
    for (int g = 0; g < 4; ++g)
      gload_lds16(Kg + (size_t)(kvb + krow0 + 8 * g) * Dm + kch,
                  &ldsK[bi][(wid * 32 + 8 * g) * 64]);
#pragma unroll
    for (int g = 0; g < 4; ++g) {
      const int dr = wid * 16 + 4 * g + vrl;
      const int vch = (vcb ^ (4 * g + vrl)) * 8;   // row&15 involution
      gload_lds16(VTg + (size_t)dr * S + kvb + vch,
                  &ldsV[bi][(wid * 16 + 4 * g) * 128]);
    }
  };

#pragma unroll 1
  for (int ph = 0; ph < 2; ++ph) {
    const int qt = ph ? (31 - pairp) : pairp;
    const int qb = qt * 64;
    const int qw = qb + wid * 16;

    bf16x8 qF[2];
#pragma unroll
    for (int kd = 0; kd < 2; ++kd)
      qF[kd] = *(const bf16x8*)&Qg[(size_t)(qw + q4) * Dm + kd * 32 + fg * 8];

    f32x4 oacc[4];
#pragma unroll
    for (int n = 0; n < 4; ++n) oacc[n] = (f32x4){0.f, 0.f, 0.f, 0.f};
    float mrow = -3.0e38f, lsum = 0.f;

    const int nTiles = (qt + 2) >> 1;

    STAGE(0, 0);
    __syncthreads();

    int buf = 0;
    for (int tile = 0; tile < nTiles; ++tile) {
      const int kvb = tile * 128;
      if (tile + 1 < nTiles) STAGE(tile + 1, buf ^ 1);
      const bf16* kb = &ldsK[buf][0];
      const bf16* vb = &ldsV[buf][0];

      // S^T = K Q^T : D[kv 0..127][q], col = q4
      f32x4 sT[8];
#pragma unroll
      for (int n = 0; n < 8; ++n) sT[n] = (f32x4){0.f, 0.f, 0.f, 0.f};
      __builtin_amdgcn_s_setprio(1);
#pragma unroll
      for (int n = 0; n < 8; ++n) {
#pragma unroll
        for (int kd = 0; kd < 2; ++kd) {
          bf16x8 kf = *(const bf16x8*)&kb[(n * 16 + q4) * 64 + (((kd * 4 + fg) ^ (q4 & 7)) * 8)];
          sT[n] = __builtin_amdgcn_mfma_f32_16x16x32_bf16(kf, qF[kd], sT[n], 0, 0, 0);
        }
      }
      __builtin_amdgcn_s_setprio(0);

      // scale into exp2 domain + causal mask (diagonal tile only)
      const bool needmask = (tile == nTiles - 1);
      const int qrow = qw + q4;
#pragma unroll
      for (int n = 0; n < 8; ++n)
#pragma unroll
        for (int r = 0; r < 4; ++r) {
          float vv = sT[n][r] * SC;
          if (needmask) {
            int kv = kvb + n * 16 + fg * 4 + r;
            if (kv > qrow) vv = -1e30f;
          }
          sT[n][r] = vv;
        }
      // row max: in-lane tree + 2 shfl
      float vm[8];
#pragma unroll
      for (int n = 0; n < 8; ++n)
        vm[n] = fmaxf(fmaxf(sT[n][0], sT[n][1]), fmaxf(sT[n][2], sT[n][3]));
      float tmax = fmaxf(fmaxf(fmaxf(vm[0], vm[1]), fmaxf(vm[2], vm[3])),
                         fmaxf(fmaxf(vm[4], vm[5]), fmaxf(vm[6], vm[7])));
      tmax = fmaxf(tmax, __shfl_xor(tmax, 16, 64));
      tmax = fmaxf(tmax, __shfl_xor(tmax, 32, 64));
      // defer-max: only rescale when max grew by > 8 (log2 units)
      if (__any(tmax > mrow + 8.f)) {
        const float mnew = fmaxf(mrow, tmax);
        const float corr = exp2fast(mrow - mnew);
        mrow = mnew;
        lsum *= corr;
#pragma unroll
        for (int n = 0; n < 4; ++n)
#pragma unroll
          for (int r = 0; r < 4; ++r) oacc[n][r] *= corr;
      }
      // P = exp2(sT - mrow), pairwise sum tree
      float rv[8];
#pragma unroll
      for (int n = 0; n < 8; ++n) {
#pragma unroll
        for (int r = 0; r < 4; ++r) sT[n][r] = exp2fast(sT[n][r] - mrow);
        rv[n] = (sT[n][0] + sT[n][1]) + (sT[n][2] + sT[n][3]);
      }
      float rs = ((rv[0] + rv[1]) + (rv[2] + rv[3])) + ((rv[4] + rv[5]) + (rv[6] + rv[7]));
      rs += __shfl_xor(rs, 16, 64);
      rs += __shfl_xor(rs, 32, 64);
      lsum += rs;

      // PV: O^T += V^T P^T (P^T B-frags built in-register via pk2 + bpermute)
#pragma unroll
      for (int ks = 0; ks < 4; ++ks) {
        const unsigned X0 = pk2(sT[2 * ks][0], sT[2 * ks][1]);
        const unsigned X1 = pk2(sT[2 * ks][2], sT[2 * ks][3]);
        const unsigned Y0 = pk2(sT[2 * ks + 1][0], sT[2 * ks + 1][1]);
        const unsigned Y1 = pk2(sT[2 * ks + 1][2], sT[2 * ks + 1][3]);
        union { int u[4]; bf16x8 v; } bfr;
        int zx, zy;
        zx = __builtin_amdgcn_ds_bpermute(idx0, (int)X0);
        zy = __builtin_amdgcn_ds_bpermute(idx0, (int)Y0);
        bfr.u[0] = (l & 32) ? zy : zx;
        zx = __builtin_amdgcn_ds_bpermute(idx0, (int)X1);
        zy = __builtin_amdgcn_ds_bpermute(idx0, (int)Y1);
        bfr.u[1] = (l & 32) ? zy : zx;
        zx = __builtin_amdgcn_ds_bpermute(idx1, (int)X0);
        zy = __builtin_amdgcn_ds_bpermute(idx1, (int)Y0);
        bfr.u[2] = (l & 32) ? zy : zx;
        zx = __builtin_amdgcn_ds_bpermute(idx1, (int)X1);
        zy = __builtin_amdgcn_ds_bpermute(idx1, (int)Y1);
        bfr.u[3] = (l & 32) ? zy : zx;
        __builtin_amdgcn_s_setprio(1);
#pragma unroll
        for (int dblk = 0; dblk < 4; ++dblk) {
          bf16x8 vf = *(const bf16x8*)&vb[(dblk * 16 + q4) * 128 + (((ks * 4 + fg) ^ q4) * 8)];
          oacc[dblk] = __builtin_amdgcn_mfma_f32_16x16x32_bf16(vf, bfr.v, oacc[dblk], 0, 0, 0);
        }
        __builtin_amdgcn_s_setprio(0);
      }
      __syncthreads();   // drains prefetch (vmcnt0) + guards buf overwrite
      buf ^= 1;
    }

    // epilogue: per-wave LDS transpose of O^T -> coalesced store (reuse ldsK)
    bf16* ldsT = &ldsK[0][0] + wid * 1152;         // 16 rows x 72 (pad) bf16
    const float inv = 1.f / lsum;
#pragma unroll
    for (int dblk = 0; dblk < 4; ++dblk)
#pragma unroll
      for (int r = 0; r < 4; ++r) {
        int d = dblk * 16 + fg * 4 + r;
        ldsT[q4 * 72 + d] = __float2bfloat16(oacc[dblk][r] * inv);
      }
    asm volatile("s_waitcnt lgkmcnt(0)" ::: "memory");
    __builtin_amdgcn_sched_barrier(0);
    const int rq = l >> 2, dq = (l & 3) * 16;
#pragma unroll
    for (int i = 0; i < 2; ++i) {
      uint4 w = *(const uint4*)&ldsT[rq * 72 + dq + 8 * i];
      *(uint4*)&Ob[((size_t)b * S + qw + rq) * Dm + h * 64 + dq + 8 * i] = w;
    }
    __syncthreads();   // epilogue LDS reads done before next phase's staging
  }
}

// ---------------------------------------------------------------- launch
extern "C" void kernel_launch(void* const* d_in, const int* in_sizes, int n_in,
                              void* d_out, int out_size, void* d_ws, size_t ws_size,
                              hipStream_t stream) {
  const float* query = (const float*)d_in[0];
  const float* key   = (const float*)d_in[1];
  const float* value = (const float*)d_in[2];
  const float* Wq = (const float*)d_in[3]; const float* bq = (const float*)d_in[4];
  const float* Wk = (const float*)d_in[5]; const float* bk = (const float*)d_in[6];
  const float* Wv = (const float*)d_in[7]; const float* bv = (const float*)d_in[8];
  const float* Wo = (const float*)d_in[9]; const float* bo = (const float*)d_in[10];
  float* out = (float*)d_out;

  char* ws = (char*)d_ws;
  const size_t MB = 1024 * 1024;
  bf16* xq  = (bf16*)(ws + 0 * MB);
  bf16* xk  = (bf16*)(ws + 8 * MB);
  bf16* xv  = (bf16*)(ws + 16 * MB);
  bf16* qp  = (bf16*)(ws + 24 * MB);
  bf16* kp  = (bf16*)(ws + 32 * MB);
  bf16* vp  = (bf16*)(ws + 40 * MB);
  bf16* WqT = (bf16*)(ws + 48 * MB);
  bf16* WkT = (bf16*)(ws + 50 * MB);
  bf16* WvT = (bf16*)(ws + 52 * MB);
  bf16* WoT = (bf16*)(ws + 54 * MB);
  bf16* VT   = xq;   // xq consumed by gemm_qkv before vtrans runs
  bf16* attn = xk;   // xk consumed by gemm_qkv before attn runs

  PrepArgs pa;
  pa.x[0] = query; pa.x[1] = key; pa.x[2] = value;
  pa.y[0] = xq; pa.y[1] = xk; pa.y[2] = xv;
  pa.W[0] = Wq; pa.W[1] = Wk; pa.W[2] = Wv; pa.W[3] = Wo;
  pa.WT[0] = WqT; pa.WT[1] = WkT; pa.WT[2] = WvT; pa.WT[3] = WoT;
  prep_kernel<<<10240, 256, 0, stream>>>(pa);

  QKVArgs qa;
  qa.A[0] = xq;  qa.A[1] = xk;  qa.A[2] = xv;
  qa.BT[0] = WqT; qa.BT[1] = WkT; qa.BT[2] = WvT;
  qa.bias[0] = bq; qa.bias[1] = bk; qa.bias[2] = bv;
  qa.out[0] = qp; qa.out[1] = kp; qa.out[2] = vp;
  gemm_qkv_kernel<<<dim3(8, 32, 3), 256, 0, stream>>>(qa);

  vtrans_kernel<<<dim3(32, 32), 256, 0, stream>>>(vp, VT);
  attn_kernel<<<dim3(16, 32), 256, 0, stream>>>(qp, kp, VT, attn);
  gemm_out_kernel<<<dim3(8, 64), 256, 0, stream>>>(attn, WoT, bo, out);
}